// Round 6
// baseline (432.538 us; speedup 1.0000x reference)
//
#include <hip/hip_runtime.h>
#include <hip/hip_bf16.h>
#include <stdint.h>

// EncoderBlock: B=4, S=1024, D=1024, H=16, DK=64, DFF=4096.
// bf16 MFMA everywhere, fp32 accum, fp32 residual spine.
// R4 changes (attention): K/V LDS staging REMOVED (L2-resident per XCD after
// swizzle; Common-mistake #7 / m169). K,V fragments loaded directly from
// global into registers; zero barriers (P-LDS is wave-local); LDS 8.7KB.
// R5: identical resubmit (R4 bench hit GPUAcquisitionTimeout — never measured).

typedef unsigned short u16;
typedef __attribute__((ext_vector_type(4))) float f32x4;
typedef __attribute__((ext_vector_type(8))) short bf16x8;
typedef __attribute__((ext_vector_type(4))) unsigned short u16x4;

__device__ __forceinline__ u16 f2b(float f) {
  unsigned int u = __builtin_bit_cast(unsigned int, f);
  u += 0x7FFFu + ((u >> 16) & 1u);   // RNE
  return (u16)(u >> 16);
}

__device__ __forceinline__ void gload_lds16(const void* g, void* l) {
  __builtin_amdgcn_global_load_lds(
      reinterpret_cast<__attribute__((address_space(1))) void*>(
          reinterpret_cast<uintptr_t>(g)),
      reinterpret_cast<__attribute__((address_space(3))) void*>(
          reinterpret_cast<uintptr_t>(l)),
      16, 0, 0);
}

#define MFMA16(a, b, c) __builtin_amdgcn_mfma_f32_16x16x32_bf16((a), (b), (c), 0, 0, 0)

// ---------------- weight cast + transpose: in fp32 [K][N] -> out bf16 [N][K]
__global__ __launch_bounds__(256) void cast_transpose(
    const float* __restrict__ in, u16* __restrict__ out, int K, int N) {
  __shared__ float tile[32][33];
  const int n0 = blockIdx.x * 32, k0 = blockIdx.y * 32;
  const int tx = threadIdx.x & 31, ty = threadIdx.x >> 5;  // 32 x 8
#pragma unroll
  for (int i = 0; i < 32; i += 8)
    tile[ty + i][tx] = in[(int64_t)(k0 + ty + i) * N + (n0 + tx)];
  __syncthreads();
#pragma unroll
  for (int i = 0; i < 32; i += 8)
    out[(int64_t)(n0 + ty + i) * K + (k0 + tx)] = f2b(tile[tx][ty + i]);
}

__global__ void pack_bias(const float* __restrict__ bq, const float* __restrict__ bk,
                          const float* __restrict__ bv, float* __restrict__ out) {
  int i = blockIdx.x * 256 + threadIdx.x;  // 3072 total
  const float* src = (i < 1024) ? bq : (i < 2048 ? bk : bv);
  out[i] = src[i & 1023];
}

// ---------------- V transpose: qkv V-part -> vt[bh][64 d][1024 s] bf16
__global__ __launch_bounds__(256) void transpose_v(
    const u16* __restrict__ qkv, u16* __restrict__ vt) {
  __shared__ u16 t[32][33];
  const int bh = blockIdx.z;
  const int b = bh >> 4, h = bh & 15;
  const int s0 = blockIdx.x * 32, d0 = blockIdx.y * 32;
  const int tx = threadIdx.x & 31, ty = threadIdx.x >> 5;  // 32 x 8
  const u16* src = qkv + (int64_t)(b * 1024) * 3072 + 2048 + h * 64;
#pragma unroll
  for (int i = 0; i < 32; i += 8)
    t[ty + i][tx] = src[(int64_t)(s0 + ty + i) * 3072 + d0 + tx];
  __syncthreads();
  u16* dst = vt + (int64_t)bh * 64 * 1024;
#pragma unroll
  for (int i = 0; i < 32; i += 8)
    dst[(int64_t)(d0 + ty + i) * 1024 + s0 + tx] = t[tx][ty + i];
}

// ---------------- LayerNorm row=1024 (torch: ddof=1, eps on std)
__global__ __launch_bounds__(256) void layernorm_k(
    const float* __restrict__ x, const float* __restrict__ alpha,
    const float* __restrict__ beta, u16* __restrict__ out) {
  const int row = blockIdx.x;
  const float4 v = ((const float4*)(x + (int64_t)row * 1024))[threadIdx.x];
  float s = v.x + v.y + v.z + v.w;
  float sq = v.x * v.x + v.y * v.y + v.z * v.z + v.w * v.w;
#pragma unroll
  for (int off = 1; off < 64; off <<= 1) {
    s += __shfl_xor(s, off, 64);
    sq += __shfl_xor(sq, off, 64);
  }
  __shared__ float ss[4], ssq[4];
  const int wid = threadIdx.x >> 6;
  if ((threadIdx.x & 63) == 0) { ss[wid] = s; ssq[wid] = sq; }
  __syncthreads();
  s = ss[0] + ss[1] + ss[2] + ss[3];
  sq = ssq[0] + ssq[1] + ssq[2] + ssq[3];
  const float mean = s * (1.0f / 1024.0f);
  float var = (sq - 1024.0f * mean * mean) * (1.0f / 1023.0f);
  var = fmaxf(var, 0.0f);
  const float inv = alpha[0] / (sqrtf(var) + 1e-6f);
  const float bt = beta[0];
  u16x4 o;
  o[0] = f2b((v.x - mean) * inv + bt);
  o[1] = f2b((v.y - mean) * inv + bt);
  o[2] = f2b((v.z - mean) * inv + bt);
  o[3] = f2b((v.w - mean) * inv + bt);
  *(u16x4*)(out + (int64_t)row * 1024 + threadIdx.x * 4) = o;
}

// ---------------- GEMM: C[M][N] = act(A[M][K] @ Bt[N][K]^T + bias) (+res)
// 128 x BN tile, BK=32, 4 waves, 2-phase dbuf pipeline, XCD swizzle.
// QSCALE: multiply (acc+bias) by 0.125 for cols<1024 (folds attn 1/sqrt(DK)).
template <int BN, bool OUT_BF16, bool RELU, bool RES, bool QSCALE = false>
__global__ __launch_bounds__(256) void gemm_bt(
    const u16* __restrict__ A, const u16* __restrict__ Bt,
    const float* __restrict__ bias, const float* __restrict__ res,
    void* __restrict__ Cout, int Ndim, int K) {
  constexpr int NF = BN / 32;  // B-frags per wave
  __shared__ u16 Alds[2][128 * 32];
  __shared__ u16 Blds[2][BN * 32];
  const int tid = threadIdx.x;
  const int wid = tid >> 6, lane = tid & 63;
  // XCD-aware chunked swizzle: contiguous work per XCD (requires nwg%8==0)
  int flat = blockIdx.y * gridDim.x + blockIdx.x;
  const int cpx = (gridDim.x * gridDim.y) >> 3;
  flat = (flat & 7) * cpx + (flat >> 3);
  const int bm0 = (flat / gridDim.x) * 128;
  const int bn0 = (flat % gridDim.x) * BN;
  const int wm = (wid >> 1) * 64, wn = (wid & 1) * (BN / 2);
  const int lrow = lane & 15, lg = lane >> 4;

  f32x4 acc[4][NF] = {};

  const int srow = tid >> 2, skoff = (tid & 3) * 8;
  const u16* Ag = A + (int64_t)(bm0 + srow) * K + skoff;
  const u16* Bg = Bt + (int64_t)(bn0 + srow) * K + skoff;
  const int64_t half = (int64_t)64 * K;

  auto stage = [&](int buf) {
    char* ad = (char*)&Alds[buf][0] + tid * 16;
    char* bd = (char*)&Blds[buf][0] + tid * 16;
    gload_lds16(Ag, ad);
    gload_lds16(Ag + half, ad + 4096);
    gload_lds16(Bg, bd);
    if (BN == 128) gload_lds16(Bg + half, bd + 4096);
    Ag += 32; Bg += 32;
  };

  const int nK = K >> 5;
  stage(0);
  __syncthreads();  // tile 0 ready
  int cur = 0;
  for (int kt = 0; kt < nK; ++kt) {
    if (kt + 1 < nK) stage(cur ^ 1);  // issue next-tile loads (overlap compute)
    bf16x8 af[4], bfr[NF];
#pragma unroll
    for (int f = 0; f < 4; ++f)
      af[f] = *(const bf16x8*)&Alds[cur][(wm + f * 16 + lrow) * 32 + lg * 8];
#pragma unroll
    for (int f = 0; f < NF; ++f)
      bfr[f] = *(const bf16x8*)&Blds[cur][(wn + f * 16 + lrow) * 32 + lg * 8];
#pragma unroll
    for (int mf = 0; mf < 4; ++mf)
#pragma unroll
      for (int nf = 0; nf < NF; ++nf)
        acc[mf][nf] = MFMA16(af[mf], bfr[nf], acc[mf][nf]);
    __syncthreads();  // drains next-tile loads; guards buf reuse
    cur ^= 1;
  }

#pragma unroll
  for (int mf = 0; mf < 4; ++mf) {
#pragma unroll
    for (int nf = 0; nf < NF; ++nf) {
      const int col = bn0 + wn + nf * 16 + lrow;
      const float bv = bias[col];
#pragma unroll
      for (int r = 0; r < 4; ++r) {
        const int row = bm0 + wm + mf * 16 + lg * 4 + r;
        float v = acc[mf][nf][r] + bv;
        if (QSCALE && col < 1024) v *= 0.125f;
        if (RELU) v = fmaxf(v, 0.0f);
        if (RES) v += res[(int64_t)row * Ndim + col];
        if (OUT_BF16)
          ((u16*)Cout)[(int64_t)row * Ndim + col] = f2b(v);
        else
          ((float*)Cout)[(int64_t)row * Ndim + col] = v;
      }
    }
  }
}

// ---------------- flash attention: grid (S/64, B*H), 256 thr = 4 waves.
// No K/V LDS staging — direct global(L2) -> register fragments, ZERO barriers.
// Q pre-scaled by 0.125 in QKV gemm; defer-max (THR=8); XCD-chunked swizzle.
__global__ __launch_bounds__(256, 4) void attention_k(
    const u16* __restrict__ qkv, const u16* __restrict__ vt,
    const int* __restrict__ mask, u16* __restrict__ ctxout) {
  // XCD-chunked swizzle: all 16 q-blocks of one bh land on one XCD
  int flat = blockIdx.y * gridDim.x + blockIdx.x;        // 1024 blocks
  flat = (flat & 7) * 128 + (flat >> 3);
  const int bh = flat >> 4;
  const int q0 = (flat & 15) * 64;
  const int b = bh >> 4, h = bh & 15;
  const int tid = threadIdx.x, wid = tid >> 6, lane = tid & 63;
  const int lrow = lane & 15, lg = lane >> 4;

  __shared__ u16 Plds[4][16 * 68];   // per-wave [16 q][64 s], stride 68

  const int64_t rs = 3072;
  const u16* Qb = qkv + (int64_t)(b * 1024) * rs + h * 64;
  const u16* Kb = Qb + 1024;
  const u16* Vtb = vt + (int64_t)bh * 64 * 1024;

  // Q fragments in registers (A-frag: m=lrow, k=lg*8+j)
  bf16x8 qf[2];
  {
    const u16* qp = Qb + (int64_t)(q0 + wid * 16 + lrow) * rs + lg * 8;
    qf[0] = *(const bf16x8*)qp;
    qf[1] = *(const bf16x8*)(qp + 32);
  }

  // per-lane fragment base pointers
  const u16* Kbase = Kb + (int64_t)lrow * rs + lg * 8;     // + (sk0+nf*16)*rs (+32)
  const u16* Vbase = Vtb + lrow * 1024 + lg * 8;           // + df*16*1024 + sk0 (+32)

  float m[4], l[4];
  f32x4 ctx[4] = {};
#pragma unroll
  for (int r = 0; r < 4; ++r) { m[r] = -1e30f; l[r] = 0.0f; }

  for (int kt = 0; kt < 16; ++kt) {
    const int sk0 = kt * 64;
    // K fragments direct from L2 (B-frag: n=lrow -> s_k, k=lg*8+j -> d)
    bf16x8 kf0[4], kf1[4];
#pragma unroll
    for (int nf = 0; nf < 4; ++nf) {
      const u16* kp = Kbase + (int64_t)(sk0 + nf * 16) * rs;
      kf0[nf] = *(const bf16x8*)kp;
      kf1[nf] = *(const bf16x8*)(kp + 32);
    }
    f32x4 sa[4];
#pragma unroll
    for (int nf = 0; nf < 4; ++nf) {
      f32x4 a = {};
      a = MFMA16(qf[0], kf0[nf], a);
      a = MFMA16(qf[1], kf1[nf], a);
      sa[nf] = a;
    }
    // V fragments issued early — latency hides under softmax VALU
    bf16x8 vf0[4], vf1[4];
#pragma unroll
    for (int df = 0; df < 4; ++df) {
      const u16* vp = Vbase + df * 16 * 1024 + sk0;
      vf0[df] = *(const bf16x8*)vp;
      vf1[df] = *(const bf16x8*)(vp + 32);
    }
    // mask
#pragma unroll
    for (int nf = 0; nf < 4; ++nf) {
      const int mval = mask[b * 1024 + sk0 + nf * 16 + lrow];
#pragma unroll
      for (int r = 0; r < 4; ++r)
        sa[nf][r] = (mval == 0) ? -1e9f : sa[nf][r];
    }
    // tile max per row
    float mxs[4];
#pragma unroll
    for (int r = 0; r < 4; ++r) {
      float mx = fmaxf(fmaxf(sa[0][r], sa[1][r]), fmaxf(sa[2][r], sa[3][r]));
#pragma unroll
      for (int off = 1; off < 16; off <<= 1) mx = fmaxf(mx, __shfl_xor(mx, off, 64));
      mxs[r] = mx;
    }
    // defer-max: rescale only if some row's max grew past THR=8
    float growth = mxs[0] - m[0];
#pragma unroll
    for (int r = 1; r < 4; ++r) growth = fmaxf(growth, mxs[r] - m[r]);
    if (!__all(growth <= 8.0f)) {
#pragma unroll
      for (int r = 0; r < 4; ++r) {
        const float mn = fmaxf(m[r], mxs[r]);
        const float fac = __expf(m[r] - mn);
        m[r] = mn;
        l[r] *= fac;
#pragma unroll
        for (int df = 0; df < 4; ++df) ctx[df][r] *= fac;
      }
    }
    float rsum[4] = {0.f, 0.f, 0.f, 0.f};
    u16 pb[4][4];
#pragma unroll
    for (int nf = 0; nf < 4; ++nf)
#pragma unroll
      for (int r = 0; r < 4; ++r) {
        const float p = __expf(sa[nf][r] - m[r]);
        rsum[r] += p;
        pb[nf][r] = f2b(p);
      }
#pragma unroll
    for (int r = 0; r < 4; ++r) {
      float t = rsum[r];
#pragma unroll
      for (int off = 1; off < 16; off <<= 1) t += __shfl_xor(t, off, 64);
      l[r] += t;
    }
    // P -> per-wave LDS (C-layout -> A-layout); wave-local, no barrier
    u16* P = &Plds[wid][0];
#pragma unroll
    for (int nf = 0; nf < 4; ++nf)
#pragma unroll
      for (int r = 0; r < 4; ++r)
        P[(lg * 4 + r) * 68 + nf * 16 + lrow] = pb[nf][r];
    bf16x8 pf0 = *(const bf16x8*)&P[lrow * 68 + lg * 8];
    bf16x8 pf1 = *(const bf16x8*)&P[lrow * 68 + 32 + lg * 8];
    // ctx += P @ V  (B-frag from vt: n=lrow -> d, k=lg*8+j -> s)
#pragma unroll
    for (int df = 0; df < 4; ++df) {
      ctx[df] = MFMA16(pf0, vf0[df], ctx[df]);
      ctx[df] = MFMA16(pf1, vf1[df], ctx[df]);
    }
  }
#pragma unroll
  for (int df = 0; df < 4; ++df)
#pragma unroll
    for (int r = 0; r < 4; ++r) {
      const int row = b * 1024 + q0 + wid * 16 + lg * 4 + r;
      const int col = h * 64 + df * 16 + lrow;
      ctxout[(int64_t)row * 1024 + col] = f2b(ctx[df][r] / l[r]);
    }
}

extern "C" void kernel_launch(void* const* d_in, const int* in_sizes, int n_in,
                              void* d_out, int out_size, void* d_ws, size_t ws_size,
                              hipStream_t stream) {
  (void)in_sizes; (void)n_in; (void)out_size; (void)ws_size;
  const float* x      = (const float*)d_in[0];
  const int*   mask   = (const int*)d_in[1];
  const float* wq     = (const float*)d_in[2];
  const float* bq     = (const float*)d_in[3];
  const float* wk     = (const float*)d_in[4];
  const float* bk     = (const float*)d_in[5];
  const float* wv     = (const float*)d_in[6];
  const float* bv     = (const float*)d_in[7];
  const float* wo     = (const float*)d_in[8];
  const float* bo     = (const float*)d_in[9];
  const float* w1     = (const float*)d_in[10];
  const float* b1     = (const float*)d_in[11];
  const float* w2     = (const float*)d_in[12];
  const float* b2     = (const float*)d_in[13];
  const float* alpha1 = (const float*)d_in[14];
  const float* beta1  = (const float*)d_in[15];
  const float* alpha2 = (const float*)d_in[16];
  const float* beta2  = (const float*)d_in[17];
  float* out = (float*)d_out;

  char* ws = (char*)d_ws;
  u16*   wqkvT = (u16*)ws;                 ws += (size_t)3072 * 1024 * 2;
  u16*   woT   = (u16*)ws;                 ws += (size_t)1024 * 1024 * 2;
  u16*   w1T   = (u16*)ws;                 ws += (size_t)4096 * 1024 * 2;
  u16*   w2T   = (u16*)ws;                 ws += (size_t)1024 * 4096 * 2;
  float* bqkv  = (float*)ws;               ws += 16384;
  u16*   xn    = (u16*)ws;                 ws += (size_t)4096 * 1024 * 2;
  u16*   qkv   = (u16*)ws;                 ws += (size_t)4096 * 3072 * 2;
  u16*   ctx   = (u16*)ws;                 ws += (size_t)4096 * 1024 * 2;
  float* x2    = (float*)ws;               ws += (size_t)4096 * 1024 * 4;
  u16*   vtb   = (u16*)ws;                 ws += (size_t)64 * 64 * 1024 * 2;
  u16*   hbuf  = qkv;  // FFN hidden aliases qkv+ctx (dead by FFN1)

  const dim3 blk(256);
  cast_transpose<<<dim3(32, 32), blk, 0, stream>>>(wq, wqkvT, 1024, 1024);
  cast_transpose<<<dim3(32, 32), blk, 0, stream>>>(wk, wqkvT + 1024 * 1024, 1024, 1024);
  cast_transpose<<<dim3(32, 32), blk, 0, stream>>>(wv, wqkvT + 2048 * 1024, 1024, 1024);
  cast_transpose<<<dim3(32, 32), blk, 0, stream>>>(wo, woT, 1024, 1024);
  cast_transpose<<<dim3(128, 32), blk, 0, stream>>>(w1, w1T, 1024, 4096);
  cast_transpose<<<dim3(32, 128), blk, 0, stream>>>(w2, w2T, 4096, 1024);
  pack_bias<<<dim3(12), blk, 0, stream>>>(bq, bk, bv, bqkv);
  layernorm_k<<<4096, blk, 0, stream>>>(x, alpha1, beta1, xn);
  gemm_bt<128, true, false, false, true><<<dim3(24, 32), blk, 0, stream>>>(
      xn, wqkvT, bqkv, nullptr, qkv, 3072, 1024);
  transpose_v<<<dim3(32, 2, 64), blk, 0, stream>>>(qkv, vtb);
  attention_k<<<dim3(16, 64), blk, 0, stream>>>(qkv, vtb, mask, ctx);
  gemm_bt<64, false, false, true><<<dim3(16, 32), blk, 0, stream>>>(
      ctx, woT, bo, x, x2, 1024, 1024);
  layernorm_k<<<4096, blk, 0, stream>>>(x2, alpha2, beta2, xn);
  gemm_bt<128, true, true, false><<<dim3(32, 32), blk, 0, stream>>>(
      xn, w1T, b1, nullptr, hbuf, 4096, 1024);
  gemm_bt<64, false, false, true><<<dim3(16, 32), blk, 0, stream>>>(
      hbuf, w2T, b2, x2, out, 1024, 4096);
}

// Round 7
// 382.878 us; speedup vs baseline: 1.1297x; 1.1297x over previous
//
#include <hip/hip_runtime.h>
#include <hip/hip_bf16.h>
#include <stdint.h>

// EncoderBlock: B=4, S=1024, D=1024, H=16, DK=64, DFF=4096.
// bf16 MFMA everywhere, fp32 accum, fp32 residual spine.
// R6 changes (attention): REVERT to R2's measured-best single-buffer staged
// K/V (coalesced global_load_lds + XOR slot swizzle, 2 barriers/tile; R4's
// direct per-lane gathers were uncoalesced -> 64x L2 transactions, -62%).
// KEEP from R3: XCD-chunked grid swizzle (FETCH 70->12MB), defer-max (T13),
// Q-prescale in QKV gemm epilogue.

typedef unsigned short u16;
typedef __attribute__((ext_vector_type(4))) float f32x4;
typedef __attribute__((ext_vector_type(8))) short bf16x8;
typedef __attribute__((ext_vector_type(4))) unsigned short u16x4;

__device__ __forceinline__ u16 f2b(float f) {
  unsigned int u = __builtin_bit_cast(unsigned int, f);
  u += 0x7FFFu + ((u >> 16) & 1u);   // RNE
  return (u16)(u >> 16);
}

__device__ __forceinline__ void gload_lds16(const void* g, void* l) {
  __builtin_amdgcn_global_load_lds(
      reinterpret_cast<__attribute__((address_space(1))) void*>(
          reinterpret_cast<uintptr_t>(g)),
      reinterpret_cast<__attribute__((address_space(3))) void*>(
          reinterpret_cast<uintptr_t>(l)),
      16, 0, 0);
}

#define MFMA16(a, b, c) __builtin_amdgcn_mfma_f32_16x16x32_bf16((a), (b), (c), 0, 0, 0)

// ---------------- weight cast + transpose: in fp32 [K][N] -> out bf16 [N][K]
__global__ __launch_bounds__(256) void cast_transpose(
    const float* __restrict__ in, u16* __restrict__ out, int K, int N) {
  __shared__ float tile[32][33];
  const int n0 = blockIdx.x * 32, k0 = blockIdx.y * 32;
  const int tx = threadIdx.x & 31, ty = threadIdx.x >> 5;  // 32 x 8
#pragma unroll
  for (int i = 0; i < 32; i += 8)
    tile[ty + i][tx] = in[(int64_t)(k0 + ty + i) * N + (n0 + tx)];
  __syncthreads();
#pragma unroll
  for (int i = 0; i < 32; i += 8)
    out[(int64_t)(n0 + ty + i) * K + (k0 + tx)] = f2b(tile[tx][ty + i]);
}

__global__ void pack_bias(const float* __restrict__ bq, const float* __restrict__ bk,
                          const float* __restrict__ bv, float* __restrict__ out) {
  int i = blockIdx.x * 256 + threadIdx.x;  // 3072 total
  const float* src = (i < 1024) ? bq : (i < 2048 ? bk : bv);
  out[i] = src[i & 1023];
}

// ---------------- V transpose: qkv V-part -> vt[bh][64 d][1024 s] bf16
__global__ __launch_bounds__(256) void transpose_v(
    const u16* __restrict__ qkv, u16* __restrict__ vt) {
  __shared__ u16 t[32][33];
  const int bh = blockIdx.z;
  const int b = bh >> 4, h = bh & 15;
  const int s0 = blockIdx.x * 32, d0 = blockIdx.y * 32;
  const int tx = threadIdx.x & 31, ty = threadIdx.x >> 5;  // 32 x 8
  const u16* src = qkv + (int64_t)(b * 1024) * 3072 + 2048 + h * 64;
#pragma unroll
  for (int i = 0; i < 32; i += 8)
    t[ty + i][tx] = src[(int64_t)(s0 + ty + i) * 3072 + d0 + tx];
  __syncthreads();
  u16* dst = vt + (int64_t)bh * 64 * 1024;
#pragma unroll
  for (int i = 0; i < 32; i += 8)
    dst[(int64_t)(d0 + ty + i) * 1024 + s0 + tx] = t[tx][ty + i];
}

// ---------------- LayerNorm row=1024 (torch: ddof=1, eps on std)
__global__ __launch_bounds__(256) void layernorm_k(
    const float* __restrict__ x, const float* __restrict__ alpha,
    const float* __restrict__ beta, u16* __restrict__ out) {
  const int row = blockIdx.x;
  const float4 v = ((const float4*)(x + (int64_t)row * 1024))[threadIdx.x];
  float s = v.x + v.y + v.z + v.w;
  float sq = v.x * v.x + v.y * v.y + v.z * v.z + v.w * v.w;
#pragma unroll
  for (int off = 1; off < 64; off <<= 1) {
    s += __shfl_xor(s, off, 64);
    sq += __shfl_xor(sq, off, 64);
  }
  __shared__ float ss[4], ssq[4];
  const int wid = threadIdx.x >> 6;
  if ((threadIdx.x & 63) == 0) { ss[wid] = s; ssq[wid] = sq; }
  __syncthreads();
  s = ss[0] + ss[1] + ss[2] + ss[3];
  sq = ssq[0] + ssq[1] + ssq[2] + ssq[3];
  const float mean = s * (1.0f / 1024.0f);
  float var = (sq - 1024.0f * mean * mean) * (1.0f / 1023.0f);
  var = fmaxf(var, 0.0f);
  const float inv = alpha[0] / (sqrtf(var) + 1e-6f);
  const float bt = beta[0];
  u16x4 o;
  o[0] = f2b((v.x - mean) * inv + bt);
  o[1] = f2b((v.y - mean) * inv + bt);
  o[2] = f2b((v.z - mean) * inv + bt);
  o[3] = f2b((v.w - mean) * inv + bt);
  *(u16x4*)(out + (int64_t)row * 1024 + threadIdx.x * 4) = o;
}

// ---------------- GEMM: C[M][N] = act(A[M][K] @ Bt[N][K]^T + bias) (+res)
// 128 x BN tile, BK=32, 4 waves, 2-phase dbuf pipeline, XCD swizzle.
// QSCALE: multiply (acc+bias) by 0.125 for cols<1024 (folds attn 1/sqrt(DK)).
template <int BN, bool OUT_BF16, bool RELU, bool RES, bool QSCALE = false>
__global__ __launch_bounds__(256) void gemm_bt(
    const u16* __restrict__ A, const u16* __restrict__ Bt,
    const float* __restrict__ bias, const float* __restrict__ res,
    void* __restrict__ Cout, int Ndim, int K) {
  constexpr int NF = BN / 32;  // B-frags per wave
  __shared__ u16 Alds[2][128 * 32];
  __shared__ u16 Blds[2][BN * 32];
  const int tid = threadIdx.x;
  const int wid = tid >> 6, lane = tid & 63;
  // XCD-aware chunked swizzle: contiguous work per XCD (requires nwg%8==0)
  int flat = blockIdx.y * gridDim.x + blockIdx.x;
  const int cpx = (gridDim.x * gridDim.y) >> 3;
  flat = (flat & 7) * cpx + (flat >> 3);
  const int bm0 = (flat / gridDim.x) * 128;
  const int bn0 = (flat % gridDim.x) * BN;
  const int wm = (wid >> 1) * 64, wn = (wid & 1) * (BN / 2);
  const int lrow = lane & 15, lg = lane >> 4;

  f32x4 acc[4][NF] = {};

  const int srow = tid >> 2, skoff = (tid & 3) * 8;
  const u16* Ag = A + (int64_t)(bm0 + srow) * K + skoff;
  const u16* Bg = Bt + (int64_t)(bn0 + srow) * K + skoff;
  const int64_t half = (int64_t)64 * K;

  auto stage = [&](int buf) {
    char* ad = (char*)&Alds[buf][0] + tid * 16;
    char* bd = (char*)&Blds[buf][0] + tid * 16;
    gload_lds16(Ag, ad);
    gload_lds16(Ag + half, ad + 4096);
    gload_lds16(Bg, bd);
    if (BN == 128) gload_lds16(Bg + half, bd + 4096);
    Ag += 32; Bg += 32;
  };

  const int nK = K >> 5;
  stage(0);
  __syncthreads();  // tile 0 ready
  int cur = 0;
  for (int kt = 0; kt < nK; ++kt) {
    if (kt + 1 < nK) stage(cur ^ 1);  // issue next-tile loads (overlap compute)
    bf16x8 af[4], bfr[NF];
#pragma unroll
    for (int f = 0; f < 4; ++f)
      af[f] = *(const bf16x8*)&Alds[cur][(wm + f * 16 + lrow) * 32 + lg * 8];
#pragma unroll
    for (int f = 0; f < NF; ++f)
      bfr[f] = *(const bf16x8*)&Blds[cur][(wn + f * 16 + lrow) * 32 + lg * 8];
#pragma unroll
    for (int mf = 0; mf < 4; ++mf)
#pragma unroll
      for (int nf = 0; nf < NF; ++nf)
        acc[mf][nf] = MFMA16(af[mf], bfr[nf], acc[mf][nf]);
    __syncthreads();  // drains next-tile loads; guards buf reuse
    cur ^= 1;
  }

#pragma unroll
  for (int mf = 0; mf < 4; ++mf) {
#pragma unroll
    for (int nf = 0; nf < NF; ++nf) {
      const int col = bn0 + wn + nf * 16 + lrow;
      const float bv = bias[col];
#pragma unroll
      for (int r = 0; r < 4; ++r) {
        const int row = bm0 + wm + mf * 16 + lg * 4 + r;
        float v = acc[mf][nf][r] + bv;
        if (QSCALE && col < 1024) v *= 0.125f;
        if (RELU) v = fmaxf(v, 0.0f);
        if (RES) v += res[(int64_t)row * Ndim + col];
        if (OUT_BF16)
          ((u16*)Cout)[(int64_t)row * Ndim + col] = f2b(v);
        else
          ((float*)Cout)[(int64_t)row * Ndim + col] = v;
      }
    }
  }
}

// ---------------- flash attention: 1024 blocks, 256 thr = 4 waves.
// Single-buffer staged K/Vt via coalesced global_load_lds, XOR slot-swizzle
// (source+read, rule #21). XCD-chunked swizzle; defer-max (THR=8);
// Q pre-scaled by 0.125 in the QKV gemm.
__global__ __launch_bounds__(256) void attention_k(
    const u16* __restrict__ qkv, const u16* __restrict__ vt,
    const int* __restrict__ mask, u16* __restrict__ ctxout) {
  // XCD-chunked swizzle: all 16 q-blocks of one bh land on one XCD
  int flat = blockIdx.y * gridDim.x + blockIdx.x;        // 1024 blocks
  flat = (flat & 7) * 128 + (flat >> 3);
  const int bh = flat >> 4;
  const int q0 = (flat & 15) * 64;
  const int b = bh >> 4, h = bh & 15;
  const int tid = threadIdx.x, wid = tid >> 6, lane = tid & 63;
  const int lrow = lane & 15, lg = lane >> 4;

  __shared__ u16 Klds[64 * 64];     // swizzled [s][slot]
  __shared__ u16 Vtlds[64 * 64];    // swizzled [d][slot]
  __shared__ u16 Plds[4][16 * 68];  // per-wave [16 q][64 s], stride 68

  const int64_t rs = 3072;
  const u16* Qb = qkv + (int64_t)(b * 1024) * rs + h * 64;
  const u16* Kb = Qb + 1024;
  const u16* Vtb = vt + (int64_t)bh * 64 * 1024;

  // Q fragments in registers (A-frag: m=lrow, k=lg*8+j)
  bf16x8 qf[2];
  {
    const u16* qp = Qb + (int64_t)(q0 + wid * 16 + lrow) * rs + lg * 8;
    qf[0] = *(const bf16x8*)qp;
    qf[1] = *(const bf16x8*)(qp + 32);
  }

  // staging: chunk c -> row=c>>3, lds slot=c&7, global slot=(c&7)^(row&7)
  const int c0 = wid * 64 + lane, c1 = 256 + c0;
  const int r0 = c0 >> 3, r1 = c1 >> 3;
  const int gq0 = (c0 & 7) ^ (r0 & 7), gq1 = (c1 & 7) ^ (r1 & 7);
  char* KldsB0 = (char*)Klds + wid * 64 * 16;
  char* KldsB1 = (char*)Klds + (256 + wid * 64) * 16;
  char* VldsB0 = (char*)Vtlds + wid * 64 * 16;
  char* VldsB1 = (char*)Vtlds + (256 + wid * 64) * 16;
  const u16* Kg0 = Kb + (int64_t)r0 * rs + gq0 * 8;
  const u16* Kg1 = Kb + (int64_t)r1 * rs + gq1 * 8;
  const u16* Vg0 = Vtb + r0 * 1024 + gq0 * 8;
  const u16* Vg1 = Vtb + r1 * 1024 + gq1 * 8;

  float m[4], l[4];
  f32x4 ctx[4] = {};
#pragma unroll
  for (int r = 0; r < 4; ++r) { m[r] = -1e30f; l[r] = 0.0f; }

  for (int kt = 0; kt < 16; ++kt) {
    const int sk0 = kt * 64;
    __syncthreads();  // prev tile fully consumed
    gload_lds16(Kg0 + (int64_t)sk0 * rs, KldsB0);
    gload_lds16(Kg1 + (int64_t)sk0 * rs, KldsB1);
    gload_lds16(Vg0 + sk0, VldsB0);
    gload_lds16(Vg1 + sk0, VldsB1);
    __syncthreads();  // tile ready

    // S = Q K^T (scale pre-folded into Q)
    f32x4 sa[4];
#pragma unroll
    for (int nf = 0; nf < 4; ++nf) {
      const int srow = nf * 16 + lrow;
      const char* kr = (const char*)Klds + srow * 128;
      bf16x8 kf0 = *(const bf16x8*)(kr + ((lg ^ (srow & 7)) * 16));
      bf16x8 kf1 = *(const bf16x8*)(kr + (((4 | lg) ^ (srow & 7)) * 16));
      f32x4 a = {};
      a = MFMA16(qf[0], kf0, a);
      a = MFMA16(qf[1], kf1, a);
      sa[nf] = a;
    }
    // mask
#pragma unroll
    for (int nf = 0; nf < 4; ++nf) {
      const int mval = mask[b * 1024 + sk0 + nf * 16 + lrow];
#pragma unroll
      for (int r = 0; r < 4; ++r)
        sa[nf][r] = (mval == 0) ? -1e9f : sa[nf][r];
    }
    // tile max per row
    float mxs[4];
#pragma unroll
    for (int r = 0; r < 4; ++r) {
      float mx = fmaxf(fmaxf(sa[0][r], sa[1][r]), fmaxf(sa[2][r], sa[3][r]));
#pragma unroll
      for (int off = 1; off < 16; off <<= 1) mx = fmaxf(mx, __shfl_xor(mx, off, 64));
      mxs[r] = mx;
    }
    // defer-max: rescale only if some row's max grew past THR=8
    float growth = mxs[0] - m[0];
#pragma unroll
    for (int r = 1; r < 4; ++r) growth = fmaxf(growth, mxs[r] - m[r]);
    if (!__all(growth <= 8.0f)) {
#pragma unroll
      for (int r = 0; r < 4; ++r) {
        const float mn = fmaxf(m[r], mxs[r]);
        const float fac = __expf(m[r] - mn);
        m[r] = mn;
        l[r] *= fac;
#pragma unroll
        for (int df = 0; df < 4; ++df) ctx[df][r] *= fac;
      }
    }
    float rsum[4] = {0.f, 0.f, 0.f, 0.f};
    u16 pb[4][4];
#pragma unroll
    for (int nf = 0; nf < 4; ++nf)
#pragma unroll
      for (int r = 0; r < 4; ++r) {
        const float p = __expf(sa[nf][r] - m[r]);
        rsum[r] += p;
        pb[nf][r] = f2b(p);
      }
#pragma unroll
    for (int r = 0; r < 4; ++r) {
      float t = rsum[r];
#pragma unroll
      for (int off = 1; off < 16; off <<= 1) t += __shfl_xor(t, off, 64);
      l[r] += t;
    }
    // P -> per-wave LDS (C-layout -> A-layout); wave-local, no barrier
    u16* P = &Plds[wid][0];
#pragma unroll
    for (int nf = 0; nf < 4; ++nf)
#pragma unroll
      for (int r = 0; r < 4; ++r)
        P[(lg * 4 + r) * 68 + nf * 16 + lrow] = pb[nf][r];
    bf16x8 pf0 = *(const bf16x8*)&P[lrow * 68 + lg * 8];
    bf16x8 pf1 = *(const bf16x8*)&P[lrow * 68 + 32 + lg * 8];
    // ctx += P @ V  (B-frag from Vt: n=lrow -> d, k=lg*8+j -> s)
#pragma unroll
    for (int df = 0; df < 4; ++df) {
      const int drow = df * 16 + lrow;
      const char* vr = (const char*)Vtlds + drow * 128;
      bf16x8 vf0 = *(const bf16x8*)(vr + ((lg ^ (drow & 7)) * 16));
      bf16x8 vf1 = *(const bf16x8*)(vr + (((4 | lg) ^ (drow & 7)) * 16));
      ctx[df] = MFMA16(pf0, vf0, ctx[df]);
      ctx[df] = MFMA16(pf1, vf1, ctx[df]);
    }
  }
#pragma unroll
  for (int df = 0; df < 4; ++df)
#pragma unroll
    for (int r = 0; r < 4; ++r) {
      const int row = b * 1024 + q0 + wid * 16 + lg * 4 + r;
      const int col = h * 64 + df * 16 + lrow;
      ctxout[(int64_t)row * 1024 + col] = f2b(ctx[df][r] / l[r]);
    }
}

extern "C" void kernel_launch(void* const* d_in, const int* in_sizes, int n_in,
                              void* d_out, int out_size, void* d_ws, size_t ws_size,
                              hipStream_t stream) {
  (void)in_sizes; (void)n_in; (void)out_size; (void)ws_size;
  const float* x      = (const float*)d_in[0];
  const int*   mask   = (const int*)d_in[1];
  const float* wq     = (const float*)d_in[2];
  const float* bq     = (const float*)d_in[3];
  const float* wk     = (const float*)d_in[4];
  const float* bk     = (const float*)d_in[5];
  const float* wv     = (const float*)d_in[6];
  const float* bv     = (const float*)d_in[7];
  const float* wo     = (const float*)d_in[8];
  const float* bo     = (const float*)d_in[9];
  const float* w1     = (const float*)d_in[10];
  const float* b1     = (const float*)d_in[11];
  const float* w2     = (const float*)d_in[12];
  const float* b2     = (const float*)d_in[13];
  const float* alpha1 = (const float*)d_in[14];
  const float* beta1  = (const float*)d_in[15];
  const float* alpha2 = (const float*)d_in[16];
  const float* beta2  = (const float*)d_in[17];
  float* out = (float*)d_out;

  char* ws = (char*)d_ws;
  u16*   wqkvT = (u16*)ws;                 ws += (size_t)3072 * 1024 * 2;
  u16*   woT   = (u16*)ws;                 ws += (size_t)1024 * 1024 * 2;
  u16*   w1T   = (u16*)ws;                 ws += (size_t)4096 * 1024 * 2;
  u16*   w2T   = (u16*)ws;                 ws += (size_t)1024 * 4096 * 2;
  float* bqkv  = (float*)ws;               ws += 16384;
  u16*   xn    = (u16*)ws;                 ws += (size_t)4096 * 1024 * 2;
  u16*   qkv   = (u16*)ws;                 ws += (size_t)4096 * 3072 * 2;
  u16*   ctx   = (u16*)ws;                 ws += (size_t)4096 * 1024 * 2;
  float* x2    = (float*)ws;               ws += (size_t)4096 * 1024 * 4;
  u16*   vtb   = (u16*)ws;                 ws += (size_t)64 * 64 * 1024 * 2;
  u16*   hbuf  = qkv;  // FFN hidden aliases qkv+ctx (dead by FFN1)

  const dim3 blk(256);
  cast_transpose<<<dim3(32, 32), blk, 0, stream>>>(wq, wqkvT, 1024, 1024);
  cast_transpose<<<dim3(32, 32), blk, 0, stream>>>(wk, wqkvT + 1024 * 1024, 1024, 1024);
  cast_transpose<<<dim3(32, 32), blk, 0, stream>>>(wv, wqkvT + 2048 * 1024, 1024, 1024);
  cast_transpose<<<dim3(32, 32), blk, 0, stream>>>(wo, woT, 1024, 1024);
  cast_transpose<<<dim3(128, 32), blk, 0, stream>>>(w1, w1T, 1024, 4096);
  cast_transpose<<<dim3(32, 128), blk, 0, stream>>>(w2, w2T, 4096, 1024);
  pack_bias<<<dim3(12), blk, 0, stream>>>(bq, bk, bv, bqkv);
  layernorm_k<<<4096, blk, 0, stream>>>(x, alpha1, beta1, xn);
  gemm_bt<128, true, false, false, true><<<dim3(24, 32), blk, 0, stream>>>(
      xn, wqkvT, bqkv, nullptr, qkv, 3072, 1024);
  transpose_v<<<dim3(32, 2, 64), blk, 0, stream>>>(qkv, vtb);
  attention_k<<<dim3(16, 64), blk, 0, stream>>>(qkv, vtb, mask, ctx);
  gemm_bt<64, false, false, true><<<dim3(16, 32), blk, 0, stream>>>(
      ctx, woT, bo, x, x2, 1024, 1024);
  layernorm_k<<<4096, blk, 0, stream>>>(x2, alpha2, beta2, xn);
  gemm_bt<128, true, true, false><<<dim3(32, 32), blk, 0, stream>>>(
      xn, w1T, b1, nullptr, hbuf, 4096, 1024);
  gemm_bt<64, false, false, true><<<dim3(16, 32), blk, 0, stream>>>(
      hbuf, w2T, b2, x2, out, 1024, 4096);
}